// Round 8
// baseline (83.570 us; speedup 1.0000x reference)
//
#include <hip/hip_runtime.h>
#include <hip/hip_bf16.h>
#include <cstdint>
#include <cstddef>

#define VOCAB  50000
#define EMBED  256
#define HIDDEN 512
#define BATCH  64
#define SEQ    200
#define H2     1024
#define XDIM   1280   // EMBED + H2
#define G3     1536   // 3*HIDDEN
#define V4     (VOCAB/4)     // 12500 float4 per row
#define NVB    782           // vocab GEMM blocks (782*64 = 50048 >= 50000)
#define NVBP   784           // Spart row stride (NVB + scc slot + pad)
#define NFB    13            // finalize chunks per row (13*4096 = 53248 >= 50000)

typedef __attribute__((ext_vector_type(8))) short short8;
typedef __attribute__((ext_vector_type(4))) float f32x4;

__device__ __forceinline__ short f2bf(float f) {
  uint32_t u = __builtin_bit_cast(uint32_t, f);
  uint32_t r = (u + 0x7fffu + ((u >> 16) & 1u)) >> 16;
  return (short)(r & 0xffffu);
}

__device__ __forceinline__ short8 pack8(float4 v0, float4 v1) {
  short8 fr;
  fr[0]=f2bf(v0.x); fr[1]=f2bf(v0.y); fr[2]=f2bf(v0.z); fr[3]=f2bf(v0.w);
  fr[4]=f2bf(v1.x); fr[5]=f2bf(v1.y); fr[6]=f2bf(v1.z); fr[7]=f2bf(v1.w);
  return fr;
}

// ---------------------------------------------------------------------------
// K1: fused GRU input GEMMs (verified since round 2).
// ---------------------------------------------------------------------------
__launch_bounds__(256)
__global__ void gru_gemm(const int* __restrict__ idx, const float* __restrict__ embed,
                         const float* __restrict__ weighted, const float* __restrict__ h0,
                         const float* __restrict__ w_ih, const float* __restrict__ w_hh,
                         float* __restrict__ gxp, float* __restrict__ ghp) {
  __shared__ __align__(16) short As[4 * 64 * 8];
  const int tid  = threadIdx.x;
  const int wave = tid >> 6, lane = tid & 63;
  const int l15  = lane & 15, lk = lane >> 4;
  const int slice = blockIdx.y;
  const bool isX  = slice < 8;
  const float* B  = isX ? w_ih : w_hh;
  const int ldb   = isX ? XDIM : HIDDEN;
  const int kbeg  = isX ? slice * 160 : (slice - 8) * 128;
  const int kend  = kbeg + (isX ? 160 : 128);
  float* C = isX ? (gxp + (size_t)slice * BATCH * G3)
                 : (ghp + (size_t)(slice - 8) * BATCH * G3);
  const int ncol = blockIdx.x * 64 + wave * 16;

  f32x4 acc0 = {0,0,0,0}, acc1 = {0,0,0,0}, acc2 = {0,0,0,0}, acc3 = {0,0,0,0};

  const int sl  = tid & 63;
  const int sm  = (tid >> 6) * 16 + (sl & 15);
  const int skb = (sl >> 4) * 8;

  const int nrow = ncol + l15;
  const float* Bbase = B + (size_t)nrow * ldb + lk * 8;

  for (int kc = kbeg; kc < kend; kc += 32) {
    {
      const float4* ap;
      if (isX) {
        int col = kc + skb;
        if (col < EMBED) ap = reinterpret_cast<const float4*>(embed + (size_t)idx[sm] * EMBED + col);
        else             ap = reinterpret_cast<const float4*>(weighted + (size_t)sm * H2 + (col - EMBED));
      } else {
        ap = reinterpret_cast<const float4*>(h0 + (size_t)sm * HIDDEN + kc + skb);
      }
      *reinterpret_cast<short8*>(&As[tid * 8]) = pack8(ap[0], ap[1]);
    }
    __syncthreads();
    short8 bf;
    {
      const float4* bp = reinterpret_cast<const float4*>(Bbase + kc);
      bf = pack8(bp[0], bp[1]);
    }
    short8 a0 = *reinterpret_cast<const short8*>(&As[(0*64 + lane)*8]);
    short8 a1 = *reinterpret_cast<const short8*>(&As[(1*64 + lane)*8]);
    short8 a2 = *reinterpret_cast<const short8*>(&As[(2*64 + lane)*8]);
    short8 a3 = *reinterpret_cast<const short8*>(&As[(3*64 + lane)*8]);
    acc0 = __builtin_amdgcn_mfma_f32_16x16x32_bf16(a0, bf, acc0, 0, 0, 0);
    acc1 = __builtin_amdgcn_mfma_f32_16x16x32_bf16(a1, bf, acc1, 0, 0, 0);
    acc2 = __builtin_amdgcn_mfma_f32_16x16x32_bf16(a2, bf, acc2, 0, 0, 0);
    acc3 = __builtin_amdgcn_mfma_f32_16x16x32_bf16(a3, bf, acc3, 0, 0, 0);
    __syncthreads();
  }

  const int n = ncol + l15;
  #pragma unroll
  for (int r = 0; r < 4; ++r) {
    C[(size_t)(0*16 + lk*4 + r) * G3 + n] = acc0[r];
    C[(size_t)(1*16 + lk*4 + r) * G3 + n] = acc1[r];
    C[(size_t)(2*16 + lk*4 + r) * G3 + n] = acc2[r];
    C[(size_t)(3*16 + lk*4 + r) * G3 + n] = acc3[r];
  }
}

// ---------------------------------------------------------------------------
// K2: GRU gates (sums 12 partial slices) + emit stateF (bf16 fragment-linear).
// ---------------------------------------------------------------------------
__launch_bounds__(256)
__global__ void gru_gates(const float* __restrict__ gxp, const float* __restrict__ ghp,
                          const float* __restrict__ b_ih, const float* __restrict__ b_hh,
                          const float* __restrict__ h0, float* __restrict__ out_state,
                          unsigned short* __restrict__ stateF) {
  int i = blockIdx.x * 256 + threadIdx.x;
  int b = i >> 9, h = i & 511;
  float xr = b_ih[h], xz = b_ih[HIDDEN + h], xn = b_ih[2*HIDDEN + h];
  #pragma unroll
  for (int s = 0; s < 8; ++s) {
    const float* g = gxp + (size_t)s * BATCH * G3 + (size_t)b * G3;
    xr += g[h]; xz += g[HIDDEN + h]; xn += g[2*HIDDEN + h];
  }
  float hr = b_hh[h], hz = b_hh[HIDDEN + h], hn = b_hh[2*HIDDEN + h];
  #pragma unroll
  for (int s = 0; s < 4; ++s) {
    const float* g = ghp + (size_t)s * BATCH * G3 + (size_t)b * G3;
    hr += g[h]; hz += g[HIDDEN + h]; hn += g[2*HIDDEN + h];
  }
  float r = 1.f / (1.f + __expf(-(xr + hr)));
  float z = 1.f / (1.f + __expf(-(xz + hz)));
  float n = tanhf(xn + r * hn);
  float st = (1.f - z) * n + z * h0[(size_t)b*HIDDEN + h];
  out_state[(size_t)b*HIDDEN + h] = st;
  int fi = ((h >> 5) * 4 + (b >> 4)) * 512 + ((b & 15) + 16 * ((h >> 3) & 3)) * 8 + (h & 7);
  stateF[fi] = (unsigned short)f2bf(st);
}

// ---------------------------------------------------------------------------
// K3: vocab GEMM v4: TRUE issue-early/use-late 2-deep register pipeline.
// Round-7 lesson: both direct and LDS-staged variants stalled ~55us because
// every chunk did load->convert->use back-to-back (wave waits vmcnt on its own
// just-issued loads, x16 chunks, and all 846 blocks are co-resident with no
// block-generation pipelining). Here chunk c+1's loads (B: 2 float4, A: 4
// short8) are ISSUED into slot (c+1)&1 before chunk c's slot is consumed;
// fully unrolled so all indices are static (no scratch). The compiler then
// waits with counted vmcnt, hiding ~1 iteration of latency per chunk, and
// 13 waves/CU of TLP covers the rest.
// NO cross-block atomics, NO LDS, NO barriers in the GEMM path.
// ---------------------------------------------------------------------------
__launch_bounds__(256)
__global__ void vocab_v4(const unsigned short* __restrict__ stateF,
                         const float* __restrict__ state,
                         const float* __restrict__ wo_w, const float* __restrict__ wo_b,
                         const int* __restrict__ eidx, const int* __restrict__ iidx,
                         const float* __restrict__ enc, const float* __restrict__ wc_w,
                         const float* __restrict__ wc_b,
                         float* __restrict__ E, float* __restrict__ escc,
                         float* __restrict__ Spart) {
  __shared__ float red[256];
  __shared__ float sval[SEQ];
  __shared__ int   act[SEQ];
  const int bid = blockIdx.x;
  const int tid = threadIdx.x;

  if (bid < BATCH) {
    // ---------------- sparse copy-score role ----------------
    const int b = bid;
    const int in0 = iidx[b];
    if (tid < SEQ) {
      int e = eidx[b*SEQ + tid];
      act[tid]  = (e != 0 && e == in0);
      sval[tid] = 0.f;
    }
    __syncthreads();
    for (int sq = 0; sq < SEQ; ++sq) {
      if (act[sq]) {
        const float4* er = reinterpret_cast<const float4*>(enc + (size_t)b*SEQ*H2 + (size_t)sq*H2);
        float part_sum = 0.f;
        for (int h = tid; h < HIDDEN; h += 256) {
          const float4* wr = reinterpret_cast<const float4*>(wc_w + (size_t)h*H2);
          float d = wc_b[h];
          for (int k = 0; k < H2/4; ++k) {
            float4 a = er[k], w = wr[k];
            d += a.x*w.x + a.y*w.y + a.z*w.z + a.w*w.w;
          }
          part_sum += tanhf(d) * state[(size_t)b*HIDDEN + h];
        }
        red[tid] = part_sum;
        __syncthreads();
        for (int off = 128; off > 0; off >>= 1) {
          if (tid < off) red[tid] += red[tid + off];
          __syncthreads();
        }
        if (tid == 0) sval[sq] = red[0];
        __syncthreads();
      }
    }
    __syncthreads();
    float ex = 0.f;
    if (tid < SEQ) {
      ex = __expf(sval[tid]);
      escc[b*SEQ + tid] = ex;
    }
    red[tid] = ex;
    __syncthreads();
    for (int off = 128; off > 0; off >>= 1) {
      if (tid < off) red[tid] += red[tid + off];
      __syncthreads();
    }
    if (tid == 0) Spart[(size_t)b * NVBP + NVB] = red[0];
    return;
  }

  // ---------------- vocab GEMM role (2-deep register pipeline) ------------
  const int vb   = bid - BATCH;
  const int wave = tid >> 6, lane = tid & 63;
  const int l15  = lane & 15, lk = lane >> 4;
  const int ncol = vb * 64 + wave * 16;
  int nrow = ncol + l15; if (nrow > VOCAB - 1) nrow = VOCAB - 1;
  const float*  Bb = wo_w + (size_t)nrow * HIDDEN + lk * 8;
  const short8* Af = reinterpret_cast<const short8*>(stateF);

  f32x4 acc0 = {0,0,0,0}, acc1 = {0,0,0,0}, acc2 = {0,0,0,0}, acc3 = {0,0,0,0};

  float4 pb0[2], pb1[2];
  short8 pa0[2], pa1[2], pa2[2], pa3[2];

  // prologue: issue chunk 0 into slot 0
  {
    const float4* bp = reinterpret_cast<const float4*>(Bb);
    pb0[0] = bp[0]; pb1[0] = bp[1];
    pa0[0] = Af[0*64 + lane]; pa1[0] = Af[1*64 + lane];
    pa2[0] = Af[2*64 + lane]; pa3[0] = Af[3*64 + lane];
  }
  #pragma unroll
  for (int c = 0; c < 16; ++c) {
    const int cur = c & 1, nxt = cur ^ 1;
    if (c < 15) {
      // ISSUE ONLY: loads for chunk c+1 (consumed next iteration)
      const float4* bp = reinterpret_cast<const float4*>(Bb + (c+1)*32);
      pb0[nxt] = bp[0]; pb1[nxt] = bp[1];
      pa0[nxt] = Af[((c+1)*4 + 0)*64 + lane];
      pa1[nxt] = Af[((c+1)*4 + 1)*64 + lane];
      pa2[nxt] = Af[((c+1)*4 + 2)*64 + lane];
      pa3[nxt] = Af[((c+1)*4 + 3)*64 + lane];
    }
    // USE: chunk c from slot cur (loads issued one iteration ago)
    short8 bf = pack8(pb0[cur], pb1[cur]);
    acc0 = __builtin_amdgcn_mfma_f32_16x16x32_bf16(pa0[cur], bf, acc0, 0, 0, 0);
    acc1 = __builtin_amdgcn_mfma_f32_16x16x32_bf16(pa1[cur], bf, acc1, 0, 0, 0);
    acc2 = __builtin_amdgcn_mfma_f32_16x16x32_bf16(pa2[cur], bf, acc2, 0, 0, 0);
    acc3 = __builtin_amdgcn_mfma_f32_16x16x32_bf16(pa3[cur], bf, acc3, 0, 0, 0);
  }

  const int n = ncol + l15;
  const bool valid = n < VOCAB;
  const float bv = valid ? wo_b[n] : 0.f;
  f32x4 accs[4] = {acc0, acc1, acc2, acc3};
  #pragma unroll
  for (int a = 0; a < 4; ++a) {
    #pragma unroll
    for (int r = 0; r < 4; ++r) {
      float ev = valid ? __expf(accs[a][r] + bv) : 0.f;
      if (valid) E[(size_t)(a*16 + lk*4 + r) * VOCAB + n] = ev;
      float v = ev;
      v += __shfl_xor(v, 1); v += __shfl_xor(v, 2);
      v += __shfl_xor(v, 4); v += __shfl_xor(v, 8);
      if (l15 == 0) red[wave*64 + a*16 + lk*4 + r] = v;   // red as 4x64 rowsums
    }
  }
  __syncthreads();
  if (tid < 64)
    Spart[(size_t)tid * NVBP + vb] =
        red[0*64+tid] + red[1*64+tid] + red[2*64+tid] + red[3*64+tid];
}

// ---------------------------------------------------------------------------
// K4: finalize + scatter + weighted_new, one dispatch. grid = BATCH + 64*NFB.
// ---------------------------------------------------------------------------
__launch_bounds__(256)
__global__ void finalize_fused(const int* __restrict__ eidx, const int* __restrict__ iidx,
                               const float* __restrict__ escc, const float* __restrict__ Spart,
                               const float* __restrict__ enc,
                               float* __restrict__ out0, float* __restrict__ wnew) {
  const int bid = blockIdx.x;
  const int tid = threadIdx.x;

  if (bid < BATCH) {
    // ---------------- weighted_new role ----------------
    __shared__ float attn_sh[SEQ];
    __shared__ float fnorm_sh;
    const int b = bid;
    const int in0 = iidx[b];
    if (tid < SEQ) {
      int e = eidx[b*SEQ + tid];
      attn_sh[tid] = (e == in0) ? escc[b*SEQ + tid] : 0.f;
    }
    __syncthreads();
    if (tid == 0) {
      float s = 0.f;
      for (int i = 0; i < SEQ; ++i) s += attn_sh[i];
      fnorm_sh = (s > 0.f) ? 1.f / s : 1.f;
    }
    __syncthreads();
    const float f = fnorm_sh;
    float a0 = 0, a1 = 0, a2 = 0, a3 = 0;
    const float4* ep = reinterpret_cast<const float4*>(enc + (size_t)b*SEQ*H2);
    for (int s = 0; s < SEQ; ++s) {
      float a = attn_sh[s];
      if (a != 0.f) {                       // block-uniform, almost always skipped
        a *= f;
        float4 v = ep[(size_t)s*(H2/4) + tid];
        a0 += a*v.x; a1 += a*v.y; a2 += a*v.z; a3 += a*v.w;
      }
    }
    float4 o = {a0, a1, a2, a3};
    reinterpret_cast<float4*>(wnew + (size_t)b*H2)[tid] = o;
    return;
  }

  __shared__ int   me[SEQ];
  __shared__ float mp[SEQ];
  __shared__ float sred[256];
  __shared__ int   cnt;
  const int q = bid - BATCH;
  const int b = q / NFB, c = q % NFB;
  if (tid == 0) cnt = 0;
  float ps = 0.f;
  for (int i = tid; i < NVB + 1; i += 256) ps += Spart[(size_t)b * NVBP + i];
  sred[tid] = ps;
  __syncthreads();
  if (tid < SEQ) {
    int e = eidx[b*SEQ + tid];
    if ((unsigned)(e - c*4096) < 4096u) {
      int j = atomicAdd(&cnt, 1);           // LDS atomic, block-local
      me[j] = e; mp[j] = escc[b*SEQ + tid];
    }
  }
  for (int off = 128; off > 0; off >>= 1) {
    __syncthreads();
    if (tid < off) sred[tid] += sred[tid + off];
  }
  __syncthreads();
  const float inv = 1.f / sred[0];
  const int ncnt = cnt;
  #pragma unroll
  for (int t = 0; t < 4; ++t) {
    const int i4 = c * 1024 + t * 256 + tid;
    if (i4 < V4) {
      float4 v = reinterpret_cast<const float4*>(out0 + (size_t)b*VOCAB)[i4];
      float4 o;
      o.x = v.x * inv; o.y = v.y * inv; o.z = v.z * inv; o.w = v.w * inv;
      const int base = i4 * 4;
      for (int j = 0; j < ncnt; ++j) {
        unsigned d = (unsigned)(me[j] - base);
        if (d < 4u) (&o.x)[d] += mp[j] * inv;
      }
      reinterpret_cast<float4*>(out0 + (size_t)b*VOCAB)[i4] = o;
    }
  }
}

// ---------------------------------------------------------------------------
extern "C" void kernel_launch(void* const* d_in, const int* in_sizes, int n_in,
                              void* d_out, int out_size, void* d_ws, size_t ws_size,
                              hipStream_t stream) {
  (void)in_sizes; (void)n_in; (void)out_size; (void)ws_size;
  const int*   input_idx  = (const int*)d_in[0];
  const float* encoded    = (const float*)d_in[1];
  const int*   enc_idx    = (const int*)d_in[2];
  const float* prev_state = (const float*)d_in[3];
  const float* weighted   = (const float*)d_in[4];
  const float* embed      = (const float*)d_in[6];
  const float* w_ih       = (const float*)d_in[7];
  const float* w_hh       = (const float*)d_in[8];
  const float* b_ih       = (const float*)d_in[9];
  const float* b_hh       = (const float*)d_in[10];
  const float* wo_w       = (const float*)d_in[11];
  const float* wo_b       = (const float*)d_in[12];
  const float* wc_w       = (const float*)d_in[13];
  const float* wc_b       = (const float*)d_in[14];

  float* out0      = (float*)d_out;                          // 64 x 50000
  float* out_state = out0 + (size_t)BATCH * VOCAB;           // 64 x 512
  float* out_wnew  = out_state + BATCH * HIDDEN;             // 64 x 1024

  // ws layout (floats): gxp(8*64*1536) | ghp(4*64*1536) | stateF(64KB)
  //                     | escc(64*200) | Spart(64*784)
  float* ws    = (float*)d_ws;
  float* gxp   = ws;
  float* ghp   = ws + (size_t)8 * BATCH * G3;
  unsigned short* stateF = (unsigned short*)(ws + (size_t)12 * BATCH * G3);
  float* escc  = ws + (size_t)12 * BATCH * G3 + 16384;
  float* Spart = escc + BATCH * SEQ;

  gru_gemm<<<dim3(G3/64, 12), 256, 0, stream>>>(input_idx, embed, weighted, prev_state,
                                                w_ih, w_hh, gxp, ghp);
  gru_gates<<<(BATCH*HIDDEN)/256, 256, 0, stream>>>(gxp, ghp, b_ih, b_hh, prev_state,
                                                    out_state, stateF);
  vocab_v4<<<BATCH + NVB, 256, 0, stream>>>(stateF, out_state, wo_w, wo_b,
                                            enc_idx, input_idx, encoded, wc_w, wc_b,
                                            out0, escc, Spart);
  finalize_fused<<<BATCH + BATCH*NFB, 256, 0, stream>>>(enc_idx, input_idx, escc, Spart,
                                                        encoded, out0, out_wnew);
}

// Round 9
// 82.291 us; speedup vs baseline: 1.0155x; 1.0155x over previous
//
#include <hip/hip_runtime.h>
#include <hip/hip_bf16.h>
#include <cstdint>
#include <cstddef>

#define VOCAB  50000
#define EMBED  256
#define HIDDEN 512
#define BATCH  64
#define SEQ    200
#define H2     1024
#define XDIM   1280   // EMBED + H2
#define G3     1536   // 3*HIDDEN
#define V4     (VOCAB/4)     // 12500 float4 per row
#define NVB    782           // vocab GEMM blocks (782*64 = 50048 >= 50000)
#define NVBP   784           // Spart row stride
#define NFB    13            // finalize chunks per row (13*4096 >= 50000)
#define NHS    8             // scc H-slices (rider parallelism per row)
#define NSCC   (BATCH*NHS)   // 512 scc rider blocks

typedef __attribute__((ext_vector_type(8))) short short8;
typedef __attribute__((ext_vector_type(4))) float f32x4;

__device__ __forceinline__ short f2bf(float f) {
  uint32_t u = __builtin_bit_cast(uint32_t, f);
  uint32_t r = (u + 0x7fffu + ((u >> 16) & 1u)) >> 16;
  return (short)(r & 0xffffu);
}

__device__ __forceinline__ short8 pack8(float4 v0, float4 v1) {
  short8 fr;
  fr[0]=f2bf(v0.x); fr[1]=f2bf(v0.y); fr[2]=f2bf(v0.z); fr[3]=f2bf(v0.w);
  fr[4]=f2bf(v1.x); fr[5]=f2bf(v1.y); fr[6]=f2bf(v1.z); fr[7]=f2bf(v1.w);
  return fr;
}

// ---------------------------------------------------------------------------
// K1: fused GRU input GEMMs (verified since round 2).
// ---------------------------------------------------------------------------
__launch_bounds__(256)
__global__ void gru_gemm(const int* __restrict__ idx, const float* __restrict__ embed,
                         const float* __restrict__ weighted, const float* __restrict__ h0,
                         const float* __restrict__ w_ih, const float* __restrict__ w_hh,
                         float* __restrict__ gxp, float* __restrict__ ghp) {
  __shared__ __align__(16) short As[4 * 64 * 8];
  const int tid  = threadIdx.x;
  const int wave = tid >> 6, lane = tid & 63;
  const int l15  = lane & 15, lk = lane >> 4;
  const int slice = blockIdx.y;
  const bool isX  = slice < 8;
  const float* B  = isX ? w_ih : w_hh;
  const int ldb   = isX ? XDIM : HIDDEN;
  const int kbeg  = isX ? slice * 160 : (slice - 8) * 128;
  const int kend  = kbeg + (isX ? 160 : 128);
  float* C = isX ? (gxp + (size_t)slice * BATCH * G3)
                 : (ghp + (size_t)(slice - 8) * BATCH * G3);
  const int ncol = blockIdx.x * 64 + wave * 16;

  f32x4 acc0 = {0,0,0,0}, acc1 = {0,0,0,0}, acc2 = {0,0,0,0}, acc3 = {0,0,0,0};

  const int sl  = tid & 63;
  const int sm  = (tid >> 6) * 16 + (sl & 15);
  const int skb = (sl >> 4) * 8;

  const int nrow = ncol + l15;
  const float* Bbase = B + (size_t)nrow * ldb + lk * 8;

  for (int kc = kbeg; kc < kend; kc += 32) {
    {
      const float4* ap;
      if (isX) {
        int col = kc + skb;
        if (col < EMBED) ap = reinterpret_cast<const float4*>(embed + (size_t)idx[sm] * EMBED + col);
        else             ap = reinterpret_cast<const float4*>(weighted + (size_t)sm * H2 + (col - EMBED));
      } else {
        ap = reinterpret_cast<const float4*>(h0 + (size_t)sm * HIDDEN + kc + skb);
      }
      *reinterpret_cast<short8*>(&As[tid * 8]) = pack8(ap[0], ap[1]);
    }
    __syncthreads();
    short8 bf;
    {
      const float4* bp = reinterpret_cast<const float4*>(Bbase + kc);
      bf = pack8(bp[0], bp[1]);
    }
    short8 a0 = *reinterpret_cast<const short8*>(&As[(0*64 + lane)*8]);
    short8 a1 = *reinterpret_cast<const short8*>(&As[(1*64 + lane)*8]);
    short8 a2 = *reinterpret_cast<const short8*>(&As[(2*64 + lane)*8]);
    short8 a3 = *reinterpret_cast<const short8*>(&As[(3*64 + lane)*8]);
    acc0 = __builtin_amdgcn_mfma_f32_16x16x32_bf16(a0, bf, acc0, 0, 0, 0);
    acc1 = __builtin_amdgcn_mfma_f32_16x16x32_bf16(a1, bf, acc1, 0, 0, 0);
    acc2 = __builtin_amdgcn_mfma_f32_16x16x32_bf16(a2, bf, acc2, 0, 0, 0);
    acc3 = __builtin_amdgcn_mfma_f32_16x16x32_bf16(a3, bf, acc3, 0, 0, 0);
    __syncthreads();
  }

  const int n = ncol + l15;
  #pragma unroll
  for (int r = 0; r < 4; ++r) {
    C[(size_t)(0*16 + lk*4 + r) * G3 + n] = acc0[r];
    C[(size_t)(1*16 + lk*4 + r) * G3 + n] = acc1[r];
    C[(size_t)(2*16 + lk*4 + r) * G3 + n] = acc2[r];
    C[(size_t)(3*16 + lk*4 + r) * G3 + n] = acc3[r];
  }
}

// ---------------------------------------------------------------------------
// K2: GRU gates (sums 12 partial slices) + emit stateF (bf16 fragment-linear).
// ---------------------------------------------------------------------------
__launch_bounds__(256)
__global__ void gru_gates(const float* __restrict__ gxp, const float* __restrict__ ghp,
                          const float* __restrict__ b_ih, const float* __restrict__ b_hh,
                          const float* __restrict__ h0, float* __restrict__ out_state,
                          unsigned short* __restrict__ stateF) {
  int i = blockIdx.x * 256 + threadIdx.x;
  int b = i >> 9, h = i & 511;
  float xr = b_ih[h], xz = b_ih[HIDDEN + h], xn = b_ih[2*HIDDEN + h];
  #pragma unroll
  for (int s = 0; s < 8; ++s) {
    const float* g = gxp + (size_t)s * BATCH * G3 + (size_t)b * G3;
    xr += g[h]; xz += g[HIDDEN + h]; xn += g[2*HIDDEN + h];
  }
  float hr = b_hh[h], hz = b_hh[HIDDEN + h], hn = b_hh[2*HIDDEN + h];
  #pragma unroll
  for (int s = 0; s < 4; ++s) {
    const float* g = ghp + (size_t)s * BATCH * G3 + (size_t)b * G3;
    hr += g[h]; hz += g[HIDDEN + h]; hn += g[2*HIDDEN + h];
  }
  float r = 1.f / (1.f + __expf(-(xr + hr)));
  float z = 1.f / (1.f + __expf(-(xz + hz)));
  float n = tanhf(xn + r * hn);
  float st = (1.f - z) * n + z * h0[(size_t)b*HIDDEN + h];
  out_state[(size_t)b*HIDDEN + h] = st;
  int fi = ((h >> 5) * 4 + (b >> 4)) * 512 + ((b & 15) + 16 * ((h >> 3) & 3)) * 8 + (h & 7);
  stateF[fi] = (unsigned short)f2bf(st);
}

// ---------------------------------------------------------------------------
// K3: vocab GEMM + exp + per-block row-sum partials + PARALLEL scc partials.
// Round-8 lesson: the old single-block-per-row scc rider serially streamed the
// whole 2 MB wc_w through one CU (latency-bound) whenever a row had an active
// (e!=0 && e==input_idx) match -> ~40-55us tail serializing the kernel, immune
// to every GEMM-path optimization. Now 8 H-slice riders per row (512 blocks,
// scheduled first), 4 threads per h (k-quartered, shfl reduce): per active
// position the 2 MB scan is spread over 8 CUs x 1024 threads -> ~2us.
// sccp[b][sq][hs] partials; consumers re-assemble exp(sum) themselves.
// ---------------------------------------------------------------------------
__launch_bounds__(256)
__global__ void vocab_v5(const unsigned short* __restrict__ stateF,
                         const float* __restrict__ state,
                         const float* __restrict__ wo_w, const float* __restrict__ wo_b,
                         const int* __restrict__ eidx, const int* __restrict__ iidx,
                         const float* __restrict__ enc, const float* __restrict__ wc_w,
                         const float* __restrict__ wc_b,
                         float* __restrict__ E, float* __restrict__ sccp,
                         float* __restrict__ Spart) {
  __shared__ float red[256];
  __shared__ int   act[SEQ];
  const int bid = blockIdx.x;
  const int tid = threadIdx.x;

  if (bid < NSCC) {
    // ------------- scc partial rider: row b, H-slice hs -------------
    const int b  = bid >> 3, hs = bid & 7;
    const int in0 = iidx[b];
    if (tid < SEQ) {
      int e = eidx[b*SEQ + tid];
      act[tid] = (e != 0 && e == in0);
      sccp[(size_t)(b*SEQ + tid)*NHS + hs] = 0.f;
    }
    __syncthreads();
    const int hl = tid >> 2, kq = tid & 3;
    const int h  = hs*64 + hl;
    const float4* wr = reinterpret_cast<const float4*>(wc_w + (size_t)h*H2) + kq*64;
    const float  sh  = state[(size_t)b*HIDDEN + h];
    const float  bh  = wc_b[h];
    for (int sq = 0; sq < SEQ; ++sq) {
      if (act[sq]) {
        const float4* er = reinterpret_cast<const float4*>(enc + (size_t)b*SEQ*H2 + (size_t)sq*H2) + kq*64;
        float d = 0.f;
        #pragma unroll 8
        for (int k = 0; k < 64; ++k) {
          float4 a = er[k], w = wr[k];
          d += a.x*w.x + a.y*w.y + a.z*w.z + a.w*w.w;
        }
        d += __shfl_xor(d, 1);
        d += __shfl_xor(d, 2);
        float ph = (kq == 0) ? tanhf(d + bh) * sh : 0.f;
        red[tid] = ph;
        __syncthreads();
        for (int off = 128; off > 0; off >>= 1) {
          if (tid < off) red[tid] += red[tid + off];
          __syncthreads();
        }
        if (tid == 0) sccp[(size_t)(b*SEQ + sq)*NHS + hs] = red[0];
        __syncthreads();
      }
    }
    return;
  }

  // ---------------- vocab GEMM role (LDS-free, barrier-free K-loop) -------
  const int vb   = bid - NSCC;
  const int wave = tid >> 6, lane = tid & 63;
  const int l15  = lane & 15, lk = lane >> 4;
  const int ncol = vb * 64 + wave * 16;
  int nrow = ncol + l15; if (nrow > VOCAB - 1) nrow = VOCAB - 1;
  const float*  Bb = wo_w + (size_t)nrow * HIDDEN + lk * 8;
  const short8* Af = reinterpret_cast<const short8*>(stateF);

  f32x4 acc0 = {0,0,0,0}, acc1 = {0,0,0,0}, acc2 = {0,0,0,0}, acc3 = {0,0,0,0};
  #pragma unroll 4
  for (int c = 0; c < 16; ++c) {
    const float4* bp = reinterpret_cast<const float4*>(Bb + c*32);
    float4 b0 = bp[0], b1 = bp[1];
    short8 a0 = Af[(c*4 + 0)*64 + lane];
    short8 a1 = Af[(c*4 + 1)*64 + lane];
    short8 a2 = Af[(c*4 + 2)*64 + lane];
    short8 a3 = Af[(c*4 + 3)*64 + lane];
    short8 bf = pack8(b0, b1);
    acc0 = __builtin_amdgcn_mfma_f32_16x16x32_bf16(a0, bf, acc0, 0, 0, 0);
    acc1 = __builtin_amdgcn_mfma_f32_16x16x32_bf16(a1, bf, acc1, 0, 0, 0);
    acc2 = __builtin_amdgcn_mfma_f32_16x16x32_bf16(a2, bf, acc2, 0, 0, 0);
    acc3 = __builtin_amdgcn_mfma_f32_16x16x32_bf16(a3, bf, acc3, 0, 0, 0);
  }

  const int n = ncol + l15;
  const bool valid = n < VOCAB;
  const float bv = valid ? wo_b[n] : 0.f;
  f32x4 accs[4] = {acc0, acc1, acc2, acc3};
  #pragma unroll
  for (int a = 0; a < 4; ++a) {
    #pragma unroll
    for (int r = 0; r < 4; ++r) {
      float ev = valid ? __expf(accs[a][r] + bv) : 0.f;
      if (valid) E[(size_t)(a*16 + lk*4 + r) * VOCAB + n] = ev;
      float v = ev;
      v += __shfl_xor(v, 1); v += __shfl_xor(v, 2);
      v += __shfl_xor(v, 4); v += __shfl_xor(v, 8);
      if (l15 == 0) red[wave*64 + a*16 + lk*4 + r] = v;   // red as 4x64 rowsums
    }
  }
  __syncthreads();
  if (tid < 64)
    Spart[(size_t)tid * NVBP + vb] =
        red[0*64+tid] + red[1*64+tid] + red[2*64+tid] + red[3*64+tid];
}

// ---------------------------------------------------------------------------
// K4: finalize + scatter + weighted_new. grid = BATCH + 64*NFB.
// Each consumer re-assembles escc = exp(sum_hs sccp) itself (200 exps, cheap)
// so no extra dependency stage is needed.
// ---------------------------------------------------------------------------
__launch_bounds__(256)
__global__ void finalize_fused(const int* __restrict__ eidx, const int* __restrict__ iidx,
                               const float* __restrict__ sccp, const float* __restrict__ Spart,
                               const float* __restrict__ enc,
                               float* __restrict__ out0, float* __restrict__ wnew) {
  const int bid = blockIdx.x;
  const int tid = threadIdx.x;

  if (bid < BATCH) {
    // ---------------- weighted_new role ----------------
    __shared__ float attn_sh[SEQ];
    __shared__ float fnorm_sh;
    const int b = bid;
    const int in0 = iidx[b];
    if (tid < SEQ) {
      float sc = 0.f;
      #pragma unroll
      for (int hs = 0; hs < NHS; ++hs) sc += sccp[(size_t)(b*SEQ + tid)*NHS + hs];
      int e = eidx[b*SEQ + tid];
      attn_sh[tid] = (e == in0) ? __expf(sc) : 0.f;
    }
    __syncthreads();
    if (tid == 0) {
      float s = 0.f;
      for (int i = 0; i < SEQ; ++i) s += attn_sh[i];
      fnorm_sh = (s > 0.f) ? 1.f / s : 1.f;
    }
    __syncthreads();
    const float f = fnorm_sh;
    float a0 = 0, a1 = 0, a2 = 0, a3 = 0;
    const float4* ep = reinterpret_cast<const float4*>(enc + (size_t)b*SEQ*H2);
    for (int s = 0; s < SEQ; ++s) {
      float a = attn_sh[s];
      if (a != 0.f) {                       // block-uniform, almost always skipped
        a *= f;
        float4 v = ep[(size_t)s*(H2/4) + tid];
        a0 += a*v.x; a1 += a*v.y; a2 += a*v.z; a3 += a*v.w;
      }
    }
    float4 o = {a0, a1, a2, a3};
    reinterpret_cast<float4*>(wnew + (size_t)b*H2)[tid] = o;
    return;
  }

  __shared__ int   me[SEQ];
  __shared__ float mp[SEQ];
  __shared__ float sred[256];
  __shared__ int   cnt;
  const int q = bid - BATCH;
  const int b = q / NFB, c = q % NFB;
  if (tid == 0) cnt = 0;
  // partial softmax denominator: Spart row slice + this thread's escc value
  float ps = 0.f;
  for (int i = tid; i < NVB; i += 256) ps += Spart[(size_t)b * NVBP + i];
  float ex = 0.f;
  int e = -1;
  if (tid < SEQ) {
    float sc = 0.f;
    #pragma unroll
    for (int hs = 0; hs < NHS; ++hs) sc += sccp[(size_t)(b*SEQ + tid)*NHS + hs];
    ex = __expf(sc);
    e = eidx[b*SEQ + tid];
  }
  sred[tid] = ps + ex;
  __syncthreads();
  if (tid < SEQ && (unsigned)(e - c*4096) < 4096u) {
    int j = atomicAdd(&cnt, 1);             // LDS atomic, block-local
    me[j] = e; mp[j] = ex;
  }
  for (int off = 128; off > 0; off >>= 1) {
    __syncthreads();
    if (tid < off) sred[tid] += sred[tid + off];
  }
  __syncthreads();
  const float inv = 1.f / sred[0];
  const int ncnt = cnt;
  #pragma unroll
  for (int t = 0; t < 4; ++t) {
    const int i4 = c * 1024 + t * 256 + tid;
    if (i4 < V4) {
      float4 v = reinterpret_cast<const float4*>(out0 + (size_t)b*VOCAB)[i4];
      float4 o;
      o.x = v.x * inv; o.y = v.y * inv; o.z = v.z * inv; o.w = v.w * inv;
      const int base = i4 * 4;
      for (int j = 0; j < ncnt; ++j) {
        unsigned d = (unsigned)(me[j] - base);
        if (d < 4u) (&o.x)[d] += mp[j] * inv;
      }
      reinterpret_cast<float4*>(out0 + (size_t)b*VOCAB)[i4] = o;
    }
  }
}

// ---------------------------------------------------------------------------
extern "C" void kernel_launch(void* const* d_in, const int* in_sizes, int n_in,
                              void* d_out, int out_size, void* d_ws, size_t ws_size,
                              hipStream_t stream) {
  (void)in_sizes; (void)n_in; (void)out_size; (void)ws_size;
  const int*   input_idx  = (const int*)d_in[0];
  const float* encoded    = (const float*)d_in[1];
  const int*   enc_idx    = (const int*)d_in[2];
  const float* prev_state = (const float*)d_in[3];
  const float* weighted   = (const float*)d_in[4];
  const float* embed      = (const float*)d_in[6];
  const float* w_ih       = (const float*)d_in[7];
  const float* w_hh       = (const float*)d_in[8];
  const float* b_ih       = (const float*)d_in[9];
  const float* b_hh       = (const float*)d_in[10];
  const float* wo_w       = (const float*)d_in[11];
  const float* wo_b       = (const float*)d_in[12];
  const float* wc_w       = (const float*)d_in[13];
  const float* wc_b       = (const float*)d_in[14];

  float* out0      = (float*)d_out;                          // 64 x 50000
  float* out_state = out0 + (size_t)BATCH * VOCAB;           // 64 x 512
  float* out_wnew  = out_state + BATCH * HIDDEN;             // 64 x 1024

  // ws layout (floats): gxp(8*64*1536) | ghp(4*64*1536) | stateF(64KB = 8192 f)
  //                     | sccp(64*200*8) | Spart(64*784)
  float* ws    = (float*)d_ws;
  float* gxp   = ws;
  float* ghp   = ws + (size_t)8 * BATCH * G3;
  unsigned short* stateF = (unsigned short*)(ws + (size_t)12 * BATCH * G3);
  float* sccp  = ws + (size_t)12 * BATCH * G3 + 8192;
  float* Spart = sccp + (size_t)BATCH * SEQ * NHS;

  gru_gemm<<<dim3(G3/64, 12), 256, 0, stream>>>(input_idx, embed, weighted, prev_state,
                                                w_ih, w_hh, gxp, ghp);
  gru_gates<<<(BATCH*HIDDEN)/256, 256, 0, stream>>>(gxp, ghp, b_ih, b_hh, prev_state,
                                                    out_state, stateF);
  vocab_v5<<<NSCC + NVB, 256, 0, stream>>>(stateF, out_state, wo_w, wo_b,
                                           enc_idx, input_idx, encoded, wc_w, wc_b,
                                           out0, sccp, Spart);
  finalize_fused<<<BATCH + BATCH*NFB, 256, 0, stream>>>(enc_idx, input_idx, sccp, Spart,
                                                        encoded, out0, out_wnew);
}